// Round 13
// baseline (159.456 us; speedup 1.0000x reference)
//
#include <hip/hip_runtime.h>

#define BB 32
#define SS 64
#define WW 30
#define EE 300
#define VDD 128
#define HH 32

typedef short bf16x8 __attribute__((ext_vector_type(8)));
typedef float f32x4 __attribute__((ext_vector_type(4)));
typedef unsigned int u32x2 __attribute__((ext_vector_type(2)));

__device__ __forceinline__ ushort f2bf(float f) {
  union { float f; unsigned u; } x; x.f = f;
  unsigned r = x.u + 0x7fffu + ((x.u >> 16) & 1u);
  return (ushort)(r >> 16);
}

// ---- K1: [qk (0..31)] [w2tp pack (32..126)] ----
__global__ __launch_bounds__(256) void k_small(
    const float* __restrict__ voice, const int* __restrict__ sent,
    const float* __restrict__ W1, const float* __restrict__ b1,
    const float* __restrict__ W2,
    float* __restrict__ Aout, ushort* __restrict__ w2tp) {
  __shared__ float sq[SS][33];
  int blk = blockIdx.x, t = threadIdx.x;
  if (blk < 32) {
    int b = blk;
    for (int o = t; o < SS * HH; o += 256) {
      int s = o >> 5, j = o & 31;
      const float* vrow = voice + ((size_t)b * SS + s) * VDD;
      float acc = b1[j];
      #pragma unroll 8
      for (int d = 0; d < VDD; ++d) acc += vrow[d] * W1[d * HH + j];
      sq[s][j] = acc;
    }
    __syncthreads();
    int sn = sent[b];
    int wv = t >> 6, ln = t & 63;
    for (int q = wv; q < SS; q += 4) {
      float acc = 0.f;
      #pragma unroll
      for (int j = 0; j < HH; ++j) acc += sq[q][j] * sq[ln][j];
      if (ln >= sn) acc -= 1e12f;
      float mx = acc;
      #pragma unroll
      for (int off = 32; off; off >>= 1) mx = fmaxf(mx, __shfl_xor(mx, off));
      float e = expf(acc - mx);
      float sm = e;
      #pragma unroll
      for (int off = 32; off; off >>= 1) sm += __shfl_xor(sm, off);
      Aout[((size_t)b * SS + q) * SS + ln] = e / sm;
    }
  } else {
    int g = (blk - 32) * 256 + t;
    if (g < 380 * 64) {
      int tI = g >> 6, lane = g & 63;
      int kc2 = tI / 19, ms = tI - kc2 * 19;
      int kc = kc2 >> 1, ks = kc2 & 1;
      int lg = lane >> 4, lr = lane & 15;
      int e = ms * 16 + lr;
      int kp0 = kc * 64 + ks * 32 + lg * 8;
      ushort v[8];
      #pragma unroll
      for (int j = 0; j < 8; ++j) {
        int kp = kp0 + j;
        int c = kp < 320 ? kp : kp - 20;
        bool ok = (e < EE) && (kp < 320 ? kp < 300 : kp < 620);
        v[j] = ok ? f2bf(W2[(size_t)c * EE + e]) : (ushort)0;
      }
      ushort* dst = w2tp + (size_t)g * 8;
      *(ushort4*)dst = *(ushort4*)&v[0];
      *(ushort4*)(dst + 4) = *(ushort4*)&v[4];
    }
  }
}

// ---- K2: Obf = mask .* (A @ V); V gathered from emb f32 DIRECTLY, inline cvt ----
__global__ __launch_bounds__(256) void k_pvg32(
    const float* __restrict__ Aout, const int* __restrict__ widx,
    const float* __restrict__ emb, const int* __restrict__ sent,
    ushort* __restrict__ obf) {
  __shared__ ushort sa[64][72];
  __shared__ ushort vt[256][72];
  int nc = blockIdx.x, b = blockIdx.y, t = threadIdx.x;
  int n0blk = nc * 256;
  for (int i = t; i < 64 * 16; i += 256) {
    int q = i >> 4, c4 = (i & 15) << 2;
    float4 f = *(const float4*)(Aout + (size_t)b * 4096 + q * 64 + c4);
    ushort4 u; u.x = f2bf(f.x); u.y = f2bf(f.y); u.z = f2bf(f.z); u.w = f2bf(f.w);
    *(ushort4*)&sa[q][c4] = u;
  }
  int kk = t >> 5, nl0 = (t & 31) << 3;
  int swz = (t & 31) & 7;
  int n = n0blk + nl0;                    // fixed per thread
  bool nok = (n + 7 < 9000);
  int w0 = n / 300, c0 = n - w0 * 300;    // c0 multiple of 4
  const int* wrowbase = widx + b * 1920;  // (b*64+k)*30
  #pragma unroll
  for (int p = 0; p < 8; ++p) {
    int k = p * 8 + kk;
    ushort v[8];
    if (nok) {
      const int* wrow = wrowbase + k * 30;
      float4 f0, f1;
      if (c0 <= 292) {
        int idx = wrow[w0];
        const float* s = emb + (size_t)idx * 300 + c0;
        f0 = *(const float4*)s;
        f1 = *(const float4*)(s + 4);
      } else {                            // c0 == 296: split 4/4 across words
        int idx0 = wrow[w0], idx1 = wrow[w0 + 1];
        f0 = *(const float4*)(emb + (size_t)idx0 * 300 + 296);
        f1 = *(const float4*)(emb + (size_t)idx1 * 300);
      }
      v[0] = f2bf(f0.x); v[1] = f2bf(f0.y); v[2] = f2bf(f0.z); v[3] = f2bf(f0.w);
      v[4] = f2bf(f1.x); v[5] = f2bf(f1.y); v[6] = f2bf(f1.z); v[7] = f2bf(f1.w);
    } else {
      #pragma unroll
      for (int j = 0; j < 8; ++j) v[j] = 0;
    }
    int c = (((k >> 3) ^ swz) << 3) + (k & 7);
    #pragma unroll
    for (int j = 0; j < 8; ++j) vt[nl0 + j][c] = v[j];
  }
  __syncthreads();
  int sn = sent[b];
  int wv = t >> 6, ln = t & 63, lr = ln & 15, lg = ln >> 4;
  int nbase = wv * 64;
  f32x4 acc[4][4];
  #pragma unroll
  for (int mt = 0; mt < 4; ++mt)
    #pragma unroll
    for (int nf = 0; nf < 4; ++nf) acc[mt][nf] = (f32x4){0.f, 0.f, 0.f, 0.f};
  #pragma unroll
  for (int ks = 0; ks < 2; ++ks) {
    if (ks * 32 < sn) {
      bf16x8 bfrag[4];
      #pragma unroll
      for (int nf = 0; nf < 4; ++nf) {
        int row = nbase + nf * 16 + lr;
        int gp = (ks * 4 + lg) ^ ((row >> 3) & 7);
        bfrag[nf] = *(const bf16x8*)&vt[row][gp << 3];
      }
      #pragma unroll
      for (int mt = 0; mt < 4; ++mt) {
        if (mt * 16 < sn) {
          bf16x8 afrag = *(const bf16x8*)&sa[mt * 16 + lr][ks * 32 + lg * 8];
          #pragma unroll
          for (int nf = 0; nf < 4; ++nf)
            acc[mt][nf] = __builtin_amdgcn_mfma_f32_16x16x32_bf16(
                afrag, bfrag[nf], acc[mt][nf], 0, 0, 0);
        }
      }
    }
  }
  #pragma unroll
  for (int mt = 0; mt < 4; ++mt) {
    #pragma unroll
    for (int nf = 0; nf < 4; ++nf) {
      int nn = n0blk + nbase + nf * 16 + lr;
      if (nn < 9000) {
        #pragma unroll
        for (int j = 0; j < 4; ++j) {
          int q = mt * 16 + lg * 4 + j;
          if (q < sn)
            obf[(size_t)(b * 64 + q) * 9000 + nn] = f2bf(acc[mt][nf][j]);
        }
      }
    }
  }
}

// ---- K3: out GEMM; ph1 gathered from emb f32 (prefetched into regs), inline cvt ----
__global__ __launch_bounds__(512) void k_outg32(
    const ushort* __restrict__ obf, const int* __restrict__ widx,
    const float* __restrict__ emb, const ushort* __restrict__ w2tp,
    const float* __restrict__ b2, const int* __restrict__ sent,
    float* __restrict__ out) {
  __shared__ ushort sb[64][324];
  __shared__ float sb2[304];
  int blk = blockIdx.x, t = threadIdx.x;
  int wv = t >> 6, ln = t & 63;
  size_t r0 = (size_t)blk * 64;
  int bbat = blk / 30;
  int rin0 = (blk % 30) * 64;
  int sn = sent[bbat];
  int liveN = sn * 30 - rin0; liveN = liveN < 0 ? 0 : (liveN > 64 ? 64 : liveN);
  for (int i = t; i < 304; i += 512) sb2[i] = (i < 300) ? b2[i] : 0.f;
  f32x4 acc[3][4];
  #pragma unroll
  for (int i = 0; i < 3; ++i)
    #pragma unroll
    for (int nf = 0; nf < 4; ++nf) acc[i][nf] = (f32x4){0.f, 0.f, 0.f, 0.f};
  int lr = ln & 15, lg = ln >> 4;

  auto COMPUTE = [&](int ph, int nfl) {
    #pragma unroll
    for (int kc = 0; kc < 5; ++kc) {
      bf16x8 bfr[4][2];
      #pragma unroll
      for (int nf = 0; nf < 4; ++nf)
        if (nf < nfl)
          #pragma unroll
          for (int ks = 0; ks < 2; ++ks)
            bfr[nf][ks] = *(const bf16x8*)&sb[nf * 16 + lr][kc * 64 + ks * 32 + lg * 8];
      #pragma unroll
      for (int i = 0; i < 3; ++i) {
        int ms = wv + 8 * i;
        if (ms < 19) {
          #pragma unroll
          for (int ks = 0; ks < 2; ++ks) {
            bf16x8 afr = *(const bf16x8*)(w2tp +
                ((size_t)(((ph * 5 + kc) * 2 + ks) * 19 + ms) * 64 + ln) * 8);
            #pragma unroll
            for (int nf = 0; nf < 4; ++nf)
              if (nf < nfl)
                acc[i][nf] = __builtin_amdgcn_mfma_f32_16x16x32_bf16(
                    afr, bfr[nf][ks], acc[i][nf], 0, 0, 0);
          }
        }
      }
    }
  };

  // ---- stage ph0 (obf), masked rows zeroed
  #pragma unroll
  for (int p = 0; p < 5; ++p) {
    int i = t + p * 512;
    int row = i / 40, c8 = (i - row * 40) * 8;
    u32x2 lo = {0, 0}, hi = {0, 0};
    if (row < liveN) {
      const ushort* s = obf + (r0 + row) * 300 + c8;
      if (c8 <= 288)      { lo = *(const u32x2*)s; hi = *(const u32x2*)(s + 4); }
      else if (c8 == 296) { lo = *(const u32x2*)s; }
    }
    *(u32x2*)&sb[row][c8] = lo;
    *(u32x2*)&sb[row][c8 + 4] = hi;
  }
  __syncthreads();

  // ---- issue ph1 (word_embeded) f32 gather loads NOW; hide under ph0 compute
  f32x4 pf[5][2];
  #pragma unroll
  for (int p = 0; p < 5; ++p) {
    int i = t + p * 512;
    int row = i / 40, c8 = (i - row * 40) * 8;
    pf[p][0] = (f32x4){0.f, 0.f, 0.f, 0.f};
    pf[p][1] = (f32x4){0.f, 0.f, 0.f, 0.f};
    int idx = widx[r0 + row];
    const float* s = emb + (size_t)idx * 300 + c8;
    if (c8 <= 288)      { pf[p][0] = *(const f32x4*)s; pf[p][1] = *(const f32x4*)(s + 4); }
    else if (c8 == 296) { pf[p][0] = *(const f32x4*)s; }
  }

  COMPUTE(0, (liveN + 15) >> 4);
  __syncthreads();

  #pragma unroll
  for (int p = 0; p < 5; ++p) {
    int i = t + p * 512;
    int row = i / 40, c8 = (i - row * 40) * 8;
    union { ushort s[4]; u32x2 u; } lo, hi;
    lo.s[0] = f2bf(pf[p][0][0]); lo.s[1] = f2bf(pf[p][0][1]);
    lo.s[2] = f2bf(pf[p][0][2]); lo.s[3] = f2bf(pf[p][0][3]);
    hi.s[0] = f2bf(pf[p][1][0]); hi.s[1] = f2bf(pf[p][1][1]);
    hi.s[2] = f2bf(pf[p][1][2]); hi.s[3] = f2bf(pf[p][1][3]);
    *(u32x2*)&sb[row][c8] = lo.u;
    *(u32x2*)&sb[row][c8 + 4] = hi.u;
  }
  __syncthreads();

  COMPUTE(1, 4);

  #pragma unroll
  for (int i = 0; i < 3; ++i) {
    int ms = wv + 8 * i;
    if (ms >= 19) continue;
    #pragma unroll
    for (int nf = 0; nf < 4; ++nf) {
      int rin = rin0 + nf * 16 + lr;
      #pragma unroll
      for (int j = 0; j < 4; ++j) {
        int e = ms * 16 + lg * 4 + j;
        if (e < 300)
          out[(size_t)(bbat * 300 + e) * 1920 + rin] = acc[i][nf][j] + sb2[e];
      }
    }
  }
}

extern "C" void kernel_launch(void* const* d_in, const int* in_sizes, int n_in,
                              void* d_out, int out_size, void* d_ws, size_t ws_size,
                              hipStream_t stream) {
  const int*   widx  = (const int*)d_in[0];
  const float* voice = (const float*)d_in[1];
  const int*   sent  = (const int*)d_in[2];
  const float* emb   = (const float*)d_in[4];
  const float* W1    = (const float*)d_in[5];
  const float* b1    = (const float*)d_in[6];
  const float* W2    = (const float*)d_in[7];
  const float* b2    = (const float*)d_in[8];
  float* out  = (float*)d_out;
  float* Aout = out + (size_t)BB * EE * SS * WW;  // O first, then A

  ushort* obf  = (ushort*)d_ws;                   // [61440][300] bf16
  ushort* w2tp = obf + (size_t)18432000;          // [380][64][8] bf16 fragment-major

  hipLaunchKernelGGL(k_small, dim3(127), dim3(256), 0, stream,
                     voice, sent, W1, b1, W2, Aout, w2tp);
  hipLaunchKernelGGL(k_pvg32, dim3(36, BB), dim3(256), 0, stream,
                     Aout, widx, emb, sent, obf);
  hipLaunchKernelGGL(k_outg32, dim3(960), dim3(512), 0, stream,
                     obf, widx, emb, w2tp, b2, sent, out);
}

// Round 14
// 127.954 us; speedup vs baseline: 1.2462x; 1.2462x over previous
//
#include <hip/hip_runtime.h>

#define BB 32
#define SS 64
#define WW 30
#define EE 300
#define VDD 128
#define HH 32

typedef short bf16x8 __attribute__((ext_vector_type(8)));
typedef float f32x4 __attribute__((ext_vector_type(4)));
typedef unsigned int u32x2 __attribute__((ext_vector_type(2)));
typedef unsigned int u32x4 __attribute__((ext_vector_type(4)));

__device__ __forceinline__ ushort f2bf(float f) {
  union { float f; unsigned u; } x; x.f = f;
  unsigned r = x.u + 0x7fffu + ((x.u >> 16) & 1u);
  return (ushort)(r >> 16);
}

#define CONV_PAIRS 1875000    // 50000*300/8 chunks of 8 floats
#define CONV_BLOCKS 4096

// ---- K0: emb f32 -> bf16 table. 16 waves/CU, 2 independent float4 loads/iter ----
__global__ __launch_bounds__(256) void k_conv2(
    const float* __restrict__ emb, ushort* __restrict__ emb16) {
  int tid = blockIdx.x * 256 + threadIdx.x;
  const int stride = CONV_BLOCKS * 256;
  for (int i = tid; i < CONV_PAIRS; i += stride) {
    f32x4 a = *(const f32x4*)(emb + (size_t)i * 8);
    f32x4 b = *(const f32x4*)(emb + (size_t)i * 8 + 4);
    union { ushort s[8]; u32x4 u; } o;
    o.s[0] = f2bf(a[0]); o.s[1] = f2bf(a[1]); o.s[2] = f2bf(a[2]); o.s[3] = f2bf(a[3]);
    o.s[4] = f2bf(b[0]); o.s[5] = f2bf(b[1]); o.s[6] = f2bf(b[2]); o.s[7] = f2bf(b[3]);
    *(u32x4*)(emb16 + (size_t)i * 8) = o.u;
  }
}

// ---- K1: [qk (0..31)] [w2tp pack (32..126)] ----
__global__ __launch_bounds__(256) void k_small(
    const float* __restrict__ voice, const int* __restrict__ sent,
    const float* __restrict__ W1, const float* __restrict__ b1,
    const float* __restrict__ W2,
    float* __restrict__ Aout, ushort* __restrict__ w2tp) {
  __shared__ float sq[SS][33];
  int blk = blockIdx.x, t = threadIdx.x;
  if (blk < 32) {
    int b = blk;
    for (int o = t; o < SS * HH; o += 256) {
      int s = o >> 5, j = o & 31;
      const float* vrow = voice + ((size_t)b * SS + s) * VDD;
      float acc = b1[j];
      #pragma unroll 8
      for (int d = 0; d < VDD; ++d) acc += vrow[d] * W1[d * HH + j];
      sq[s][j] = acc;
    }
    __syncthreads();
    int sn = sent[b];
    int wv = t >> 6, ln = t & 63;
    for (int q = wv; q < SS; q += 4) {
      float acc = 0.f;
      #pragma unroll
      for (int j = 0; j < HH; ++j) acc += sq[q][j] * sq[ln][j];
      if (ln >= sn) acc -= 1e12f;
      float mx = acc;
      #pragma unroll
      for (int off = 32; off; off >>= 1) mx = fmaxf(mx, __shfl_xor(mx, off));
      float e = expf(acc - mx);
      float sm = e;
      #pragma unroll
      for (int off = 32; off; off >>= 1) sm += __shfl_xor(sm, off);
      Aout[((size_t)b * SS + q) * SS + ln] = e / sm;
    }
  } else {
    int g = (blk - 32) * 256 + t;
    if (g < 380 * 64) {
      int tI = g >> 6, lane = g & 63;
      int kc2 = tI / 19, ms = tI - kc2 * 19;
      int kc = kc2 >> 1, ks = kc2 & 1;
      int lg = lane >> 4, lr = lane & 15;
      int e = ms * 16 + lr;
      int kp0 = kc * 64 + ks * 32 + lg * 8;
      ushort v[8];
      #pragma unroll
      for (int j = 0; j < 8; ++j) {
        int kp = kp0 + j;
        int c = kp < 320 ? kp : kp - 20;
        bool ok = (e < EE) && (kp < 320 ? kp < 300 : kp < 620);
        v[j] = ok ? f2bf(W2[(size_t)c * EE + e]) : (ushort)0;
      }
      ushort* dst = w2tp + (size_t)g * 8;
      *(ushort4*)dst = *(ushort4*)&v[0];
      *(ushort4*)(dst + 4) = *(ushort4*)&v[4];
    }
  }
}

// ---- K2: Obf = mask .* (A @ V); V gathered from L3-hot bf16 table ----
__global__ __launch_bounds__(256) void k_pvg(
    const float* __restrict__ Aout, const int* __restrict__ widx,
    const ushort* __restrict__ emb16, const int* __restrict__ sent,
    ushort* __restrict__ obf) {
  __shared__ ushort sa[64][72];
  __shared__ ushort vt[256][72];
  int nc = blockIdx.x, b = blockIdx.y, t = threadIdx.x;
  int n0blk = nc * 256;
  for (int i = t; i < 64 * 16; i += 256) {
    int q = i >> 4, c4 = (i & 15) << 2;
    float4 f = *(const float4*)(Aout + (size_t)b * 4096 + q * 64 + c4);
    ushort4 u; u.x = f2bf(f.x); u.y = f2bf(f.y); u.z = f2bf(f.z); u.w = f2bf(f.w);
    *(ushort4*)&sa[q][c4] = u;
  }
  int kk = t >> 5, nl0 = (t & 31) << 3;
  int swz = (t & 31) & 7;
  int n = n0blk + nl0;
  bool nok = (n + 7 < 9000);
  int w0 = n / 300, c0 = n - w0 * 300;
  const int* wrowbase = widx + b * 1920;
  #pragma unroll
  for (int p = 0; p < 8; ++p) {
    int k = p * 8 + kk;
    ushort v[8];
    if (nok) {
      const int* wrow = wrowbase + k * 30;
      if (c0 <= 292) {
        int idx = wrow[w0];
        const ushort* s = emb16 + (size_t)idx * 300 + c0;
        *(ushort4*)&v[0] = *(const ushort4*)s;
        *(ushort4*)&v[4] = *(const ushort4*)(s + 4);
      } else {
        int idx0 = wrow[w0], idx1 = wrow[w0 + 1];
        *(ushort4*)&v[0] = *(const ushort4*)(emb16 + (size_t)idx0 * 300 + 296);
        *(ushort4*)&v[4] = *(const ushort4*)(emb16 + (size_t)idx1 * 300);
      }
    } else {
      #pragma unroll
      for (int j = 0; j < 8; ++j) v[j] = 0;
    }
    int c = (((k >> 3) ^ swz) << 3) + (k & 7);
    #pragma unroll
    for (int j = 0; j < 8; ++j) vt[nl0 + j][c] = v[j];
  }
  __syncthreads();
  int sn = sent[b];
  int wv = t >> 6, ln = t & 63, lr = ln & 15, lg = ln >> 4;
  int nbase = wv * 64;
  f32x4 acc[4][4];
  #pragma unroll
  for (int mt = 0; mt < 4; ++mt)
    #pragma unroll
    for (int nf = 0; nf < 4; ++nf) acc[mt][nf] = (f32x4){0.f, 0.f, 0.f, 0.f};
  #pragma unroll
  for (int ks = 0; ks < 2; ++ks) {
    if (ks * 32 < sn) {
      bf16x8 bfrag[4];
      #pragma unroll
      for (int nf = 0; nf < 4; ++nf) {
        int row = nbase + nf * 16 + lr;
        int gp = (ks * 4 + lg) ^ ((row >> 3) & 7);
        bfrag[nf] = *(const bf16x8*)&vt[row][gp << 3];
      }
      #pragma unroll
      for (int mt = 0; mt < 4; ++mt) {
        if (mt * 16 < sn) {
          bf16x8 afrag = *(const bf16x8*)&sa[mt * 16 + lr][ks * 32 + lg * 8];
          #pragma unroll
          for (int nf = 0; nf < 4; ++nf)
            acc[mt][nf] = __builtin_amdgcn_mfma_f32_16x16x32_bf16(
                afrag, bfrag[nf], acc[mt][nf], 0, 0, 0);
        }
      }
    }
  }
  #pragma unroll
  for (int mt = 0; mt < 4; ++mt) {
    #pragma unroll
    for (int nf = 0; nf < 4; ++nf) {
      int nn = n0blk + nbase + nf * 16 + lr;
      if (nn < 9000) {
        #pragma unroll
        for (int j = 0; j < 4; ++j) {
          int q = mt * 16 + lg * 4 + j;
          if (q < sn)
            obf[(size_t)(b * 64 + q) * 9000 + nn] = f2bf(acc[mt][nf][j]);
        }
      }
    }
  }
}

// ---- K3: out GEMM; ph1 gathered from bf16 table (reg-prefetched under ph0) ----
__global__ __launch_bounds__(512) void k_outg(
    const ushort* __restrict__ obf, const int* __restrict__ widx,
    const ushort* __restrict__ emb16, const ushort* __restrict__ w2tp,
    const float* __restrict__ b2, const int* __restrict__ sent,
    float* __restrict__ out) {
  __shared__ ushort sb[64][324];
  __shared__ float sb2[304];
  int blk = blockIdx.x, t = threadIdx.x;
  int wv = t >> 6, ln = t & 63;
  size_t r0 = (size_t)blk * 64;
  int bbat = blk / 30;
  int rin0 = (blk % 30) * 64;
  int sn = sent[bbat];
  int liveN = sn * 30 - rin0; liveN = liveN < 0 ? 0 : (liveN > 64 ? 64 : liveN);
  for (int i = t; i < 304; i += 512) sb2[i] = (i < 300) ? b2[i] : 0.f;
  f32x4 acc[3][4];
  #pragma unroll
  for (int i = 0; i < 3; ++i)
    #pragma unroll
    for (int nf = 0; nf < 4; ++nf) acc[i][nf] = (f32x4){0.f, 0.f, 0.f, 0.f};
  int lr = ln & 15, lg = ln >> 4;

  auto COMPUTE = [&](int ph, int nfl) {
    #pragma unroll
    for (int kc = 0; kc < 5; ++kc) {
      bf16x8 bfr[4][2];
      #pragma unroll
      for (int nf = 0; nf < 4; ++nf)
        if (nf < nfl)
          #pragma unroll
          for (int ks = 0; ks < 2; ++ks)
            bfr[nf][ks] = *(const bf16x8*)&sb[nf * 16 + lr][kc * 64 + ks * 32 + lg * 8];
      #pragma unroll
      for (int i = 0; i < 3; ++i) {
        int ms = wv + 8 * i;
        if (ms < 19) {
          #pragma unroll
          for (int ks = 0; ks < 2; ++ks) {
            bf16x8 afr = *(const bf16x8*)(w2tp +
                ((size_t)(((ph * 5 + kc) * 2 + ks) * 19 + ms) * 64 + ln) * 8);
            #pragma unroll
            for (int nf = 0; nf < 4; ++nf)
              if (nf < nfl)
                acc[i][nf] = __builtin_amdgcn_mfma_f32_16x16x32_bf16(
                    afr, bfr[nf][ks], acc[i][nf], 0, 0, 0);
          }
        }
      }
    }
  };

  // ---- stage ph0 (obf), masked rows zeroed
  #pragma unroll
  for (int p = 0; p < 5; ++p) {
    int i = t + p * 512;
    int row = i / 40, c8 = (i - row * 40) * 8;
    u32x2 lo = {0, 0}, hi = {0, 0};
    if (row < liveN) {
      const ushort* s = obf + (r0 + row) * 300 + c8;
      if (c8 <= 288)      { lo = *(const u32x2*)s; hi = *(const u32x2*)(s + 4); }
      else if (c8 == 296) { lo = *(const u32x2*)s; }
    }
    *(u32x2*)&sb[row][c8] = lo;
    *(u32x2*)&sb[row][c8 + 4] = hi;
  }
  __syncthreads();

  // ---- issue ph1 (word_embeded from bf16 table) loads NOW; hide under ph0 compute
  u32x2 plo[5], phi[5];
  #pragma unroll
  for (int p = 0; p < 5; ++p) {
    int i = t + p * 512;
    int row = i / 40, c8 = (i - row * 40) * 8;
    plo[p] = (u32x2){0, 0}; phi[p] = (u32x2){0, 0};
    int idx = widx[r0 + row];
    const ushort* s = emb16 + (size_t)idx * 300 + c8;
    if (c8 <= 288)      { plo[p] = *(const u32x2*)s; phi[p] = *(const u32x2*)(s + 4); }
    else if (c8 == 296) { plo[p] = *(const u32x2*)s; }
  }

  COMPUTE(0, (liveN + 15) >> 4);
  __syncthreads();

  #pragma unroll
  for (int p = 0; p < 5; ++p) {
    int i = t + p * 512;
    int row = i / 40, c8 = (i - row * 40) * 8;
    *(u32x2*)&sb[row][c8] = plo[p];
    *(u32x2*)&sb[row][c8 + 4] = phi[p];
  }
  __syncthreads();

  COMPUTE(1, 4);

  #pragma unroll
  for (int i = 0; i < 3; ++i) {
    int ms = wv + 8 * i;
    if (ms >= 19) continue;
    #pragma unroll
    for (int nf = 0; nf < 4; ++nf) {
      int rin = rin0 + nf * 16 + lr;
      #pragma unroll
      for (int j = 0; j < 4; ++j) {
        int e = ms * 16 + lg * 4 + j;
        if (e < 300)
          out[(size_t)(bbat * 300 + e) * 1920 + rin] = acc[i][nf][j] + sb2[e];
      }
    }
  }
}

extern "C" void kernel_launch(void* const* d_in, const int* in_sizes, int n_in,
                              void* d_out, int out_size, void* d_ws, size_t ws_size,
                              hipStream_t stream) {
  const int*   widx  = (const int*)d_in[0];
  const float* voice = (const float*)d_in[1];
  const int*   sent  = (const int*)d_in[2];
  const float* emb   = (const float*)d_in[4];
  const float* W1    = (const float*)d_in[5];
  const float* b1    = (const float*)d_in[6];
  const float* W2    = (const float*)d_in[7];
  const float* b2    = (const float*)d_in[8];
  float* out  = (float*)d_out;
  float* Aout = out + (size_t)BB * EE * SS * WW;  // O first, then A

  ushort* emb16 = (ushort*)d_ws;                  // [50000][300] bf16
  ushort* obf   = emb16 + (size_t)18432000;       // [61440][300] bf16
  ushort* w2tp  = obf + (size_t)18432000;         // [380][64][8] bf16 fragment-major

  hipLaunchKernelGGL(k_conv2, dim3(CONV_BLOCKS), dim3(256), 0, stream, emb, emb16);
  hipLaunchKernelGGL(k_small, dim3(127), dim3(256), 0, stream,
                     voice, sent, W1, b1, W2, Aout, w2tp);
  hipLaunchKernelGGL(k_pvg, dim3(36, BB), dim3(256), 0, stream,
                     Aout, widx, emb16, sent, obf);
  hipLaunchKernelGGL(k_outg, dim3(960), dim3(512), 0, stream,
                     obf, widx, emb16, w2tp, b2, sent, out);
}